// Round 8
// baseline (243.565 us; speedup 1.0000x reference)
//
#include <hip/hip_runtime.h>
#include <hip/hip_bf16.h>

// Problem constants: N=50000, K=32, D=128.
#define D     128
#define TWO_D 256
#define KNB   32

typedef __attribute__((ext_vector_type(8))) short    s8;   // 8 x 16-bit (4 VGPR)
typedef __attribute__((ext_vector_type(8))) _Float16 h8;   // mfma operand view
typedef __attribute__((ext_vector_type(2))) _Float16 h2v;
typedef __attribute__((ext_vector_type(4))) float    f4;   // MFMA acc

__device__ inline unsigned short f2h(float f) {
    return __builtin_bit_cast(unsigned short, (_Float16)f);
}
__device__ inline float h2f(unsigned int u) {
    return (float)__builtin_bit_cast(_Float16, (unsigned short)u);
}

union v16u { s8 s; h2v h[4]; };

// 8-elem fp16 dot with f32 accumulate; v_dot2_f32_f16 when available.
__device__ inline float dot8(s8 x, s8 w, float acc) {
#if __has_builtin(__builtin_amdgcn_fdot2)
    v16u ux, uw; ux.s = x; uw.s = w;
#pragma unroll
    for (int j = 0; j < 4; ++j)
        acc = __builtin_amdgcn_fdot2(ux.h[j], uw.h[j], acc, false);
#else
#pragma unroll
    for (int j = 0; j < 8; ++j)
        acc = fmaf(h2f((unsigned short)x[j]), h2f((unsigned short)w[j]), acc);
#endif
    return acc;
}

// Async global->LDS, 16 B per lane. Global addr per-lane; LDS dest =
// wave-uniform base + lane*16 (m104 semantics; r7-proven pattern).
__device__ __forceinline__ void gload16(const void* g, void* l) {
    __builtin_amdgcn_global_load_lds(
        (__attribute__((address_space(1))) void*)g,
        (__attribute__((address_space(3))) void*)l, 16, 0, 0);
}

// ---------------------------------------------------------------------------
// Cast kernel: v_fea,t_emb -> fp16 (6250 blocks) and W -> fp16 (64 blocks).
// ---------------------------------------------------------------------------
__global__ __launch_bounds__(256) void cast_kernel(
    const float* __restrict__ a, const float* __restrict__ b,
    const float* __restrict__ Wsrc,
    unsigned short* __restrict__ oa, unsigned short* __restrict__ ob,
    unsigned short* __restrict__ oW, int n4, int nblkAB, int n4w)
{
    int bid = blockIdx.x;
    if (bid < nblkAB) {
        int i = bid * 256 + threadIdx.x;
        if (i >= n4) return;
        float4 x = ((const float4*)a)[i];
        float4 y = ((const float4*)b)[i];
        ((ushort4*)oa)[i] = make_ushort4(f2h(x.x), f2h(x.y), f2h(x.z), f2h(x.w));
        ((ushort4*)ob)[i] = make_ushort4(f2h(y.x), f2h(y.y), f2h(y.z), f2h(y.w));
    } else {
        int i = (bid - nblkAB) * 256 + threadIdx.x;
        if (i >= n4w) return;
        float4 x = ((const float4*)Wsrc)[i];
        ((ushort4*)oW)[i] = make_ushort4(f2h(x.x), f2h(x.y), f2h(x.z), f2h(x.w));
    }
}

// ---------------------------------------------------------------------------
// Kernel A: wq = [vh | th] @ Wh^T, K=256 in ONE shot (no K-loop, 1 barrier).
// Block: 64 A-rows x 64 W-rows. LDS: A 32 KB + B 32 KB (XOR-swizzled 16B
// blocks: addr = row*512 + ((kblk ^ (row&7))*16) -> 2-way banks, no pad).
// 4 waves; wave ww: m-tile rows [ww*16, ww*16+16), 4 n-tiles, 8 k-steps.
// ---------------------------------------------------------------------------
__global__ __launch_bounds__(256) void gemm_wq_mfma(
    const unsigned short* __restrict__ vh, const unsigned short* __restrict__ th,
    const unsigned short* __restrict__ Wh, unsigned short* __restrict__ wq_h, int M)
{
    __shared__ unsigned short Atile[64 * 256];   // 32 KB
    __shared__ unsigned short Btile[64 * 256];   // 32 KB

    const int tid  = threadIdx.x;
    const int ww   = tid >> 6;
    const int lane = tid & 63;
    const int quad = lane >> 4;
    const int l16  = lane & 15;
    const int row0 = blockIdx.x * 64;
    const int i0   = blockIdx.y * 64;

    // Staging: thread t -> row t>>2, 64-elem segment t&3 (8 x s8 each).
    const int sr = tid >> 2, ss = tid & 3;
    int ga = row0 + sr; if (ga >= M) ga = M - 1;          // clamp, stores guarded
    const unsigned short* asrc = ((ss < 2) ? vh : th) + (size_t)ga * D + (ss & 1) * 64;
    const unsigned short* bsrc = Wh + (size_t)(i0 + sr) * TWO_D + ss * 64;

    s8 av[8], bv[8];
#pragma unroll
    for (int m = 0; m < 8; ++m) av[m] = *(const s8*)(asrc + m * 8);
#pragma unroll
    for (int m = 0; m < 8; ++m) bv[m] = *(const s8*)(bsrc + m * 8);
#pragma unroll
    for (int m = 0; m < 8; ++m) {
        int kblk = ss * 8 + m;
        *(s8*)&Atile[sr * 256 + ((kblk ^ (sr & 7)) * 8)] = av[m];
        *(s8*)&Btile[sr * 256 + ((kblk ^ (sr & 7)) * 8)] = bv[m];
    }
    __syncthreads();   // the ONLY barrier

    f4 acc[4] = {};
    const int ar = ww * 16 + l16;                 // A LDS row for this lane
#pragma unroll
    for (int s = 0; s < 8; ++s) {
        int ablk = (s * 4 + quad) ^ (ar & 7);
        s8 af = *(const s8*)&Atile[ar * 256 + ablk * 8];
#pragma unroll
        for (int nt = 0; nt < 4; ++nt) {
            int br = nt * 16 + l16;
            int bblk = (s * 4 + quad) ^ (br & 7);
            s8 bf = *(const s8*)&Btile[br * 256 + bblk * 8];
            acc[nt] = __builtin_amdgcn_mfma_f32_16x16x32_f16(
                __builtin_bit_cast(h8, af), __builtin_bit_cast(h8, bf), acc[nt], 0, 0, 0);
        }
    }

    // Epilogue: D layout col=lane&15, row=quad*4+r.
#pragma unroll
    for (int nt = 0; nt < 4; ++nt) {
#pragma unroll
        for (int r = 0; r < 4; ++r) {
            int grow = row0 + ww * 16 + quad * 4 + r;
            if (grow < M)
                wq_h[(size_t)grow * TWO_D + i0 + nt * 16 + l16] = f2h(acc[nt][r]);
        }
    }
}

// ---------------------------------------------------------------------------
// Kernel B: gather + score + softmax + weighted sum.
// 256 thr = 4 waves = 2 rows; 2 waves per row (wsub=0/1), 18 KB LDS/row:
//   [0..16K)  16 chunks of 1 KB: [v(e_even)|v(e_odd)|t(e_even)|t(e_odd)]
//   [16384)   wq row (512 B used of 1 KB)
//   [16896)   score partials 2 x 32 f
//   [17408)   wsum partials  2 x 128 f   -> 18432 B/row, 36 KB/block,
//   4 blocks/CU = 16 waves/CU (2x round-7 occupancy).
// Phase A: wave wsub loads its 8 chunks async (wsub 0 also wq); 1 barrier.
// Scores: lane (k=lane&31, tsel=lane>>5) dots its 64-elem slice
//   [wsub*64..+64) of the (edge k, half tsel) row; fold tsel via xor32;
//   partials summed across waves via LDS. Softmax per wave (duplicated).
// Wsum: wave wsub covers its 16 edges, lane dims (lane&31)*4, parity lane>>5;
//   fold via xor32 + LDS partial; wave 0 stores.
// ---------------------------------------------------------------------------
__global__ __launch_bounds__(256) void attn_kernel(
    const unsigned short* __restrict__ vh, const unsigned short* __restrict__ th,
    const int* __restrict__ ef, const unsigned short* __restrict__ wq_h,
    float* __restrict__ outp, int M)
{
    __shared__ char L[2][18432];

    const int lane = threadIdx.x & 63;
    const int wid  = threadIdx.x >> 6;     // 0..3
    const int rib  = wid >> 1;             // row in block
    const int wsub = wid & 1;              // wave within row
    const int n    = blockIdx.x * 2 + rib; // grid*2 == M (50000)

    char* Lw = &L[rib][0];
    const int l16  = lane & 15;
    const int gsel = (lane >> 4) & 1;      // 0: even edge, 1: odd edge
    const unsigned short* gsrc = (lane < 32) ? vh : th;

    int eidx = 0;
    if (lane < KNB) eidx = ef[n * KNB + lane];

    // ---- Phase A: async direct-to-LDS (8 chunks per wave + wq on wsub 0) ----
    if (wsub == 0)
        gload16(wq_h + (size_t)n * TWO_D + lane * 8, Lw + 16384);
#pragma unroll
    for (int c = 0; c < 8; ++c) {
        int kk = wsub * 8 + c;
        int e  = __shfl(eidx, 2 * kk + gsel, 64);
        gload16(gsrc + (size_t)e * D + l16 * 8, Lw + kk * 1024);
    }
    __syncthreads();   // vmcnt drain: all chunks + wq landed

    // ---- Scores: 64-elem slice per lane ----
    const int k     = lane & 31;
    const int tsel  = lane >> 5;
    const int dbase = (k >> 1) * 1024 + (k & 1) * 256 + tsel * 512 + wsub * 128;
    const int cbase = 16384 + tsel * 256 + wsub * 128;
    float p = 0.f;
#pragma unroll
    for (int j = 0; j < 8; ++j) {
        int jl = ((j + lane) & 7) * 16;    // bank rotation
        s8 x = *(const s8*)(Lw + dbase + jl);
        s8 c = *(const s8*)(Lw + cbase + jl);
        p = dot8(x, c, p);
    }
    p += __shfl_xor(p, 32, 64);            // fold v+t: lane k<32 holds slice sum
    if (lane < 32) *(float*)(Lw + 16896 + wsub * 128 + k * 4) = p;
    __syncthreads();

    float s = *(const float*)(Lw + 16896 + k * 4)
            + *(const float*)(Lw + 16896 + 128 + k * 4);
    // softmax over k=0..31 (upper lane half mirrors it; r valid in all lanes)
    float mx = s;
#pragma unroll
    for (int off = 16; off > 0; off >>= 1) mx = fmaxf(mx, __shfl_xor(mx, off, 64));
    float ex  = __expf(s - mx);
    float sum = ex;
#pragma unroll
    for (int off = 16; off > 0; off >>= 1) sum += __shfl_xor(sum, off, 64);
    float r = ex / sum;

    // ---- Weighted sum: this wave's 16 edges ----
    float o4[4] = {0.f, 0.f, 0.f, 0.f};
    const int g   = lane >> 5;             // edge parity
    const int dby = (lane & 31) * 8;       // 4 dims (8 B fp16)
#pragma unroll
    for (int c = 0; c < 8; ++c) {
        int kk = wsub * 8 + c;
        float rk = __shfl(r, 2 * kk + g, 64);
        uint2 pq = *(const uint2*)(Lw + kk * 1024 + g * 256 + dby);
        o4[0] = fmaf(rk, h2f(pq.x & 0xFFFFu), o4[0]);
        o4[1] = fmaf(rk, h2f(pq.x >> 16),     o4[1]);
        o4[2] = fmaf(rk, h2f(pq.y & 0xFFFFu), o4[2]);
        o4[3] = fmaf(rk, h2f(pq.y >> 16),     o4[3]);
    }
#pragma unroll
    for (int j = 0; j < 4; ++j) o4[j] += __shfl_xor(o4[j], 32, 64);
    if (lane < 32)
        *(float4*)(Lw + 17408 + wsub * 512 + lane * 16) =
            make_float4(o4[0], o4[1], o4[2], o4[3]);
    __syncthreads();

    if (wsub == 0 && lane < 32) {
        float4 a = *(const float4*)(Lw + 17408 + lane * 16);
        float4 b = *(const float4*)(Lw + 17408 + 512 + lane * 16);
        *(float4*)(outp + (size_t)n * D + lane * 4) =
            make_float4(a.x + b.x, a.y + b.y, a.z + b.z, a.w + b.w);
    }
}

// ---------------------------------------------------------------------------
extern "C" void kernel_launch(void* const* d_in, const int* in_sizes, int n_in,
                              void* d_out, int out_size, void* d_ws, size_t ws_size,
                              hipStream_t stream)
{
    const float* v_fea = (const float*)d_in[0];
    const float* t_emb = (const float*)d_in[1];
    const int*   ef    = (const int*)d_in[2];
    const float* W     = (const float*)d_in[3];
    float* outp = (float*)d_out;

    const int M = in_sizes[0] / D;                  // 50000
    // ws: wq_h (25.6 MB) | vh (12.8) | th (12.8) | Wh (128 KB)
    char* ws = (char*)d_ws;
    unsigned short* wq_h = (unsigned short*)ws;
    unsigned short* vh   = (unsigned short*)(ws + (size_t)M * TWO_D * 2);
    unsigned short* th   = (unsigned short*)(ws + (size_t)M * TWO_D * 2 + (size_t)M * D * 2);
    unsigned short* Wh   = (unsigned short*)(ws + (size_t)M * TWO_D * 2 + 2 * (size_t)M * D * 2);

    const int n4     = M * D / 4;                   // 1.6M float4 per array
    const int nblkAB = (n4 + 255) / 256;            // 6250
    const int n4w    = TWO_D * TWO_D / 4;           // 16384
    const int nblkW  = (n4w + 255) / 256;           // 64
    cast_kernel<<<nblkAB + nblkW, 256, 0, stream>>>(v_fea, t_emb, W, vh, th, Wh,
                                                    n4, nblkAB, n4w);

    dim3 gg((M + 63) / 64, 4);
    gemm_wq_mfma<<<gg, 256, 0, stream>>>(vh, th, Wh, wq_h, M);
    attn_kernel<<<M / 2, 256, 0, stream>>>(vh, th, ef, wq_h, outp, M);
}

// Round 9
// 236.826 us; speedup vs baseline: 1.0285x; 1.0285x over previous
//
#include <hip/hip_runtime.h>
#include <hip/hip_bf16.h>

// Problem constants: N=50000, K=32, D=128.
#define D     128
#define TWO_D 256
#define KNB   32

typedef __attribute__((ext_vector_type(8))) short    s8;   // 8 x 16-bit (4 VGPR)
typedef __attribute__((ext_vector_type(8))) _Float16 h8;   // mfma operand view
typedef __attribute__((ext_vector_type(2))) _Float16 h2v;  // packed fp16 pair
typedef __attribute__((ext_vector_type(4))) float    f4;   // MFMA acc

__device__ inline unsigned short f2h(float f) {
    return __builtin_bit_cast(unsigned short, (_Float16)f);
}

union v16u { s8 s; h2v h[4]; };

// 8-elem fp16 dot with f32 accumulate (v_dot2_f32_f16).
__device__ inline float dot8(s8 x, s8 w, float acc) {
#if __has_builtin(__builtin_amdgcn_fdot2)
    v16u ux, uw; ux.s = x; uw.s = w;
#pragma unroll
    for (int j = 0; j < 4; ++j)
        acc = __builtin_amdgcn_fdot2(ux.h[j], uw.h[j], acc, false);
#else
    v16u ux, uw; ux.s = x; uw.s = w;
#pragma unroll
    for (int j = 0; j < 4; ++j) {
        acc = fmaf((float)ux.h[j][0], (float)uw.h[j][0], acc);
        acc = fmaf((float)ux.h[j][1], (float)uw.h[j][1], acc);
    }
#endif
    return acc;
}

// Async global->LDS, 16 B per lane. LDS dest = wave-uniform base + lane*16.
__device__ __forceinline__ void gload16(const void* g, void* l) {
    __builtin_amdgcn_global_load_lds(
        (__attribute__((address_space(1))) void*)g,
        (__attribute__((address_space(3))) void*)l, 16, 0, 0);
}

// ---------------------------------------------------------------------------
// Cast kernel: builds interleaved g[m] = [v[m] | t[m]] (256 fp16 = 512 B rows)
// and Wh (fp16 W). ~13 us.
// ---------------------------------------------------------------------------
__global__ __launch_bounds__(256) void cast_kernel(
    const float* __restrict__ a, const float* __restrict__ b,
    const float* __restrict__ Wsrc,
    unsigned short* __restrict__ g, unsigned short* __restrict__ Wh,
    int ntot, int nblkAB, int n4w)
{
    int bid = blockIdx.x;
    if (bid < nblkAB) {
        int i = bid * 256 + threadIdx.x;       // i over M*32 (row m, quarter dq)
        if (i >= ntot) return;
        int m = i >> 5, dq = i & 31;
        float4 x = *(const float4*)(a + (size_t)m * D + dq * 4);
        float4 y = *(const float4*)(b + (size_t)m * D + dq * 4);
        *(ushort4*)(g + (size_t)m * TWO_D + dq * 4) =
            make_ushort4(f2h(x.x), f2h(x.y), f2h(x.z), f2h(x.w));
        *(ushort4*)(g + (size_t)m * TWO_D + D + dq * 4) =
            make_ushort4(f2h(y.x), f2h(y.y), f2h(y.z), f2h(y.w));
    } else {
        int i = (bid - nblkAB) * 256 + threadIdx.x;
        if (i >= n4w) return;
        float4 x = ((const float4*)Wsrc)[i];
        ((ushort4*)Wh)[i] = make_ushort4(f2h(x.x), f2h(x.y), f2h(x.z), f2h(x.w));
    }
}

// ---------------------------------------------------------------------------
// Kernel A: wq = g @ Wh^T. "Stream A in registers, cache B in LDS quarters."
// Block: 64 A-rows (wave ww owns rows ww*16..+16; full K=256 held as 8 s8 =
// 32 VGPR, loaded ONCE -> A traffic 25.6 MB total). Loop 4 quarters of Wh
// (64 rows x 256 k fp16 = 32 KB LDS, XOR-swizzled 16B blocks), 32 MFMA each.
// Quarter q+1's global loads issue before quarter q's compute (prefetch).
// ---------------------------------------------------------------------------
__global__ __launch_bounds__(256) void gemm_wq_mfma(
    const unsigned short* __restrict__ g, const unsigned short* __restrict__ Wh,
    unsigned short* __restrict__ wq_h, int M)
{
    __shared__ unsigned short Btile[64 * 256];   // 32 KB

    const int tid  = threadIdx.x;
    const int ww   = tid >> 6;
    const int lane = tid & 63;
    const int quad = lane >> 4;
    const int l16  = lane & 15;
    const int row0 = blockIdx.x * 64;

    // A fragments for this lane's row, all of K. Loaded once.
    int arow = row0 + ww * 16 + l16; if (arow >= M) arow = M - 1;
    const unsigned short* ap = g + (size_t)arow * TWO_D;
    s8 af[8];
#pragma unroll
    for (int s = 0; s < 8; ++s) af[s] = *(const s8*)(ap + s * 32 + quad * 8);

    // B staging mapping: thread -> row sr (of 64), 8 16B-blocks b = ss*8+m.
    const int sr = tid >> 2, ss = tid & 3;

    // Stage quarter 0.
    s8 bv[8];
    {
        const unsigned short* bp = Wh + (size_t)sr * TWO_D + ss * 64;
#pragma unroll
        for (int m = 0; m < 8; ++m) bv[m] = *(const s8*)(bp + m * 8);
    }
#pragma unroll
    for (int m = 0; m < 8; ++m) {
        int b = ss * 8 + m, swb = (b & 24) | ((b ^ (sr & 7)) & 7);
        *(s8*)&Btile[sr * TWO_D + swb * 8] = bv[m];
    }
    __syncthreads();

    for (int q = 0; q < 4; ++q) {
        // Prefetch next quarter (global loads in flight during compute).
        if (q < 3) {
            const unsigned short* bp = Wh + (size_t)((q + 1) * 64 + sr) * TWO_D + ss * 64;
#pragma unroll
            for (int m = 0; m < 8; ++m) bv[m] = *(const s8*)(bp + m * 8);
        }

        f4 acc[4] = {};
#pragma unroll
        for (int s = 0; s < 8; ++s) {
#pragma unroll
            for (int nt = 0; nt < 4; ++nt) {
                int brow = nt * 16 + l16;
                int b = s * 4 + quad, swb = (b & 24) | ((b ^ (brow & 7)) & 7);
                s8 bf = *(const s8*)&Btile[brow * TWO_D + swb * 8];
                acc[nt] = __builtin_amdgcn_mfma_f32_16x16x32_f16(
                    __builtin_bit_cast(h8, af[s]), __builtin_bit_cast(h8, bf),
                    acc[nt], 0, 0, 0);
            }
        }

        // Epilogue for this quarter: D layout col=lane&15, row=quad*4+r.
#pragma unroll
        for (int nt = 0; nt < 4; ++nt) {
#pragma unroll
            for (int r = 0; r < 4; ++r) {
                int grow = row0 + ww * 16 + quad * 4 + r;
                if (grow < M)
                    wq_h[(size_t)grow * TWO_D + q * 64 + nt * 16 + l16] = f2h(acc[nt][r]);
            }
        }

        if (q < 3) {
            __syncthreads();   // all reads of quarter q done
#pragma unroll
            for (int m = 0; m < 8; ++m) {
                int b = ss * 8 + m, swb = (b & 24) | ((b ^ (sr & 7)) & 7);
                *(s8*)&Btile[sr * TWO_D + swb * 8] = bv[m];
            }
            __syncthreads();
        }
    }
}

// ---------------------------------------------------------------------------
// Kernel B: gather + score + softmax + weighted sum.
// 256 thr = 4 waves = 2 rows; 2 waves per row (wsub). LDS per row (18944 B):
//   [0)      16 chunks x 1024: chunk kk = [edge 2kk (v|t) 512 B | edge 2kk+1]
//   [16384)  wq row (512 used of 1024)
//   [17408)  score partials 2 x 32 f32        (256 B)
//   [17664)  wsum partials  2 x 32 x 8 B fp16 (512 B)   -> 37888/block, 4/CU.
// Phase A: wave wsub async-loads its 8 chunks (1 instr = 2 full edges);
// wsub 0 adds wq. One barrier drain. Scores: lane (k, tsel) dots 64-elem
// slice; fold xor32 + LDS partial. Softmax per-wave. Wsum: packed fp16 fma.
// ---------------------------------------------------------------------------
__global__ __launch_bounds__(256) void attn_kernel(
    const unsigned short* __restrict__ g, const int* __restrict__ ef,
    const unsigned short* __restrict__ wq_h, float* __restrict__ outp, int M)
{
    __shared__ char L[2][18944];

    const int lane = threadIdx.x & 63;
    const int wid  = threadIdx.x >> 6;     // 0..3
    const int rib  = wid >> 1;             // row in block
    const int wsub = wid & 1;              // wave within row
    const int n    = blockIdx.x * 2 + rib; // grid*2 == M (50000)

    char* Lw = &L[rib][0];
    const int l32 = lane & 31;

    int eidx = 0;
    if (lane < KNB) eidx = ef[n * KNB + lane];

    // ---- Phase A: async direct-to-LDS. 1 instr = 2 edges (1 KB chunk). ----
    if (wsub == 0)
        gload16(wq_h + (size_t)n * TWO_D + lane * 8, Lw + 16384);
#pragma unroll
    for (int c = 0; c < 8; ++c) {
        int kk = wsub * 8 + c;
        int e0 = __shfl(eidx, 2 * kk, 64);
        int e1 = __shfl(eidx, 2 * kk + 1, 64);
        int e  = (lane < 32) ? e0 : e1;
        gload16(g + (size_t)e * TWO_D + l32 * 8, Lw + kk * 1024);
    }
    __syncthreads();   // vmcnt drain: all chunks + wq landed

    // ---- Scores: lane (k = lane&31, tsel = lane>>5) dots its 64-elem slice
    //      [wsub*64 ..) of half tsel of edge k. ----
    const int k     = l32;
    const int tsel  = lane >> 5;
    const int dbase = (k >> 1) * 1024 + (k & 1) * 512 + tsel * 256 + wsub * 128;
    const int cbase = 16384 + tsel * 256 + wsub * 128;
    float p = 0.f;
#pragma unroll
    for (int j = 0; j < 8; ++j) {
        int jl = ((j + lane) & 7) * 16;    // bank rotation
        s8 x = *(const s8*)(Lw + dbase + jl);
        s8 c = *(const s8*)(Lw + cbase + jl);
        p = dot8(x, c, p);
    }
    p += __shfl_xor(p, 32, 64);            // fold v+t halves
    if (lane < 32) *(float*)(Lw + 17408 + wsub * 128 + k * 4) = p;
    __syncthreads();

    float s = *(const float*)(Lw + 17408 + k * 4)
            + *(const float*)(Lw + 17408 + 128 + k * 4);
    float mx = s;
#pragma unroll
    for (int off = 16; off > 0; off >>= 1) mx = fmaxf(mx, __shfl_xor(mx, off, 64));
    float ex  = __expf(s - mx);
    float sum = ex;
#pragma unroll
    for (int off = 16; off > 0; off >>= 1) sum += __shfl_xor(sum, off, 64);
    float r = ex / sum;                    // weight for edge k (valid all lanes)

    // ---- Weighted sum (packed fp16): lane covers dims (lane&31)*4..+3,
    //      parity gg = lane>>5; wave wsub covers chunks wsub*8..+8. ----
    const int gg  = lane >> 5;
    const int dby = l32 * 8;               // byte offset into 256 B v-part
    h2v o0 = {(_Float16)0.f, (_Float16)0.f}, o1 = o0;
#pragma unroll
    for (int c = 0; c < 8; ++c) {
        int kk = wsub * 8 + c;
        float rk = __shfl(r, 2 * kk + gg, 64);
        _Float16 rh = (_Float16)rk;
        h2v rr = {rh, rh};
        const h2v* px = (const h2v*)(Lw + kk * 1024 + gg * 512 + dby);
        o0 = px[0] * rr + o0;
        o1 = px[1] * rr + o1;
    }
    {   // fold even/odd edge parity (xor32)
        unsigned int u0 = __shfl_xor(__builtin_bit_cast(unsigned int, o0), 32, 64);
        unsigned int u1 = __shfl_xor(__builtin_bit_cast(unsigned int, o1), 32, 64);
        o0 = o0 + __builtin_bit_cast(h2v, u0);
        o1 = o1 + __builtin_bit_cast(h2v, u1);
    }
    if (lane < 32) {
        *(h2v*)(Lw + 17664 + wsub * 256 + lane * 8)     = o0;
        *(h2v*)(Lw + 17664 + wsub * 256 + lane * 8 + 4) = o1;
    }
    __syncthreads();

    if (wsub == 0 && lane < 32) {
        const h2v* pa = (const h2v*)(Lw + 17664 + lane * 8);
        const h2v* pb = (const h2v*)(Lw + 17664 + 256 + lane * 8);
        h2v a0 = pa[0] + pb[0];
        h2v a1 = pa[1] + pb[1];
        *(float4*)(outp + (size_t)n * D + lane * 4) =
            make_float4((float)a0[0], (float)a0[1], (float)a1[0], (float)a1[1]);
    }
}

// ---------------------------------------------------------------------------
extern "C" void kernel_launch(void* const* d_in, const int* in_sizes, int n_in,
                              void* d_out, int out_size, void* d_ws, size_t ws_size,
                              hipStream_t stream)
{
    const float* v_fea = (const float*)d_in[0];
    const float* t_emb = (const float*)d_in[1];
    const int*   ef    = (const int*)d_in[2];
    const float* W     = (const float*)d_in[3];
    float* outp = (float*)d_out;

    const int M = in_sizes[0] / D;                  // 50000
    // ws: wq_h (25.6 MB) | g interleaved (25.6 MB) | Wh (128 KB)
    char* ws = (char*)d_ws;
    unsigned short* wq_h = (unsigned short*)ws;
    unsigned short* g    = (unsigned short*)(ws + (size_t)M * TWO_D * 2);
    unsigned short* Wh   = (unsigned short*)(ws + 2 * (size_t)M * TWO_D * 2);

    const int ntot   = M * 32;                      // (row, quarter) pairs
    const int nblkAB = (ntot + 255) / 256;          // 6250
    const int n4w    = TWO_D * TWO_D / 4;           // 16384
    const int nblkW  = (n4w + 255) / 256;           // 64
    cast_kernel<<<nblkAB + nblkW, 256, 0, stream>>>(v_fea, t_emb, W, g, Wh,
                                                    ntot, nblkAB, n4w);

    gemm_wq_mfma<<<(M + 63) / 64, 256, 0, stream>>>(g, Wh, wq_h, M);
    attn_kernel<<<M / 2, 256, 0, stream>>>(g, ef, wq_h, outp, M);
}